// Round 6
// baseline (339.505 us; speedup 1.0000x reference)
//
#include <hip/hip_runtime.h>
#include <stdint.h>

#define NROWS 8192
#define MCOLS 8192
#define KDIM  256

typedef __bf16 bf16x8 __attribute__((ext_vector_type(8)));
typedef float  floatx4 __attribute__((ext_vector_type(4)));
typedef unsigned short ushort4v __attribute__((ext_vector_type(4)));

__device__ __forceinline__ unsigned short f32_to_bf16_rne(float f) {
    unsigned int u = __float_as_uint(f);
    u += 0x7FFFu + ((u >> 16) & 1u);   // round-to-nearest-even
    return (unsigned short)(u >> 16);
}
__device__ __forceinline__ float bf16_to_f32(unsigned short h) {
    return __uint_as_float(((unsigned int)h) << 16);
}

// async 16B global -> LDS (wave-uniform base + lane*16 pattern required)
__device__ __forceinline__ void async16(const void* g, void* l) {
    __builtin_amdgcn_global_load_lds(
        (const __attribute__((address_space(1))) unsigned int*)g,
        (__attribute__((address_space(3))) unsigned int*)l,
        16, 0, 0);
}

// ---------------- kernel 1: row prep with FUSED alpha softmax ----------------
// Each block redundantly computes sa = sqrt(softmax(araw^2)) (256 elems, cheap,
// araw L2-hot) -> one fewer kernel launch. Then one row per WAVE, float4/lane.
__global__ void prep_rows(const float* __restrict__ x1, const float* __restrict__ x2,
                          const float* __restrict__ araw,
                          unsigned short* __restrict__ Amat, unsigned short* __restrict__ Bmat,
                          float* __restrict__ ra, float* __restrict__ rb) {
    __shared__ float sa_lds[256];
    __shared__ float wred[8];
    int tid  = threadIdx.x;
    int wave = tid >> 6;
    int lane = tid & 63;

    // fused softmax (all 256 threads)
    float z = araw[tid];
    z = z * z;
    float m = z;
#pragma unroll
    for (int off = 32; off; off >>= 1) m = fmaxf(m, __shfl_xor(m, off));
    if (lane == 0) wred[wave] = m;
    __syncthreads();
    float mx = fmaxf(fmaxf(wred[0], wred[1]), fmaxf(wred[2], wred[3]));
    float e = __expf(z - mx);
    float s = e;
#pragma unroll
    for (int off = 32; off; off >>= 1) s += __shfl_xor(s, off);
    if (lane == 0) wred[4 + wave] = s;       // disjoint slots: no extra barrier
    __syncthreads();
    float sum = wred[4] + wred[5] + wred[6] + wred[7];
    sa_lds[tid] = sqrtf(e / sum);
    __syncthreads();

    // row scaling: one row per wave
    int grow = blockIdx.x * 4 + wave;          // 0 .. 16383
    const float* x; unsigned short* mat; float* nrm; int row;
    if (grow < NROWS) { x = x1; mat = Amat; nrm = ra; row = grow; }
    else              { x = x2; mat = Bmat; nrm = rb; row = grow - NROWS; }

    floatx4 v  = *(const floatx4*)&x[(size_t)row * KDIM + lane * 4];
    floatx4 sv = *(const floatx4*)&sa_lds[lane * 4];
    ushort4v h;
    float p = 0.0f;
#pragma unroll
    for (int j = 0; j < 4; ++j) {
        float f = v[j] * sv[j];
        unsigned short hh = f32_to_bf16_rne(f);
        h[j] = hh;
        float fv = bf16_to_f32(hh);
        p += fv * fv;
    }
    *(ushort4v*)&mat[(size_t)row * KDIM + lane * 4] = h;
#pragma unroll
    for (int off = 32; off; off >>= 1) p += __shfl_xor(p, off);
    if (lane == 0) nrm[row] = p;
}

// ---------------- kernel 2: persistent NT-GEMM + fused RBF epilogue ----------
// out = var*exp(-0.5*max(ra_i - 2*sum_k A[i,k]B[j,k] + rb_j, 0))
// v5 theory: the invariant ~120us across v0-v4 is the per-tile serial chain
//   stage -> vmcnt(0)+barrier -> compute (x4) -> epilogue, with no intra-block
//   overlap between a tile's epilogue and the next tile's staging.
// Fix: PERSISTENT blocks (2048 blocks x 2 tiles). After the last compute
//   barrier of tile T, issue tile T+1's K0 stage, THEN run T's epilogue
//   (no LDS use) -> the ~2000cy epilogue hides the next stage's L2 latency.
// Single 32 KiB LDS buffer + __launch_bounds__(256,4) keeps 4 blocks/CU
//   (exactly 2 balanced rounds of 1024 resident blocks).
// Kept: transposed acc (mfma(b,a)) -> dwordx4 stores, XCD-slab swizzle
//   (tiles g and g+2048 share g&7 -> same slab), XOR LDS swizzle.
__global__ __launch_bounds__(256, 4) void rbf_gemm(
    const unsigned short* __restrict__ A, const unsigned short* __restrict__ B,
    const float* __restrict__ ra, const float* __restrict__ rb,
    const float* __restrict__ vraw, float* __restrict__ out)
{
    __shared__ unsigned short As[128 * 64];   // 16 KiB
    __shared__ unsigned short Bs[128 * 64];   // 16 KiB

    const int tid  = threadIdx.x;
    const int lane = tid & 63;
    const int wave = tid >> 6;

    const int wm = (wave & 1) * 64;
    const int wn = (wave >> 1) * 64;
    const int quad = lane >> 4;
    const int l15  = lane & 15;

    // tile ids for this persistent block; XCD-slab swizzle per tile
    int bmv[2], bnv[2];
#pragma unroll
    for (int tt = 0; tt < 2; ++tt) {
        int g   = blockIdx.x + tt * 2048;    // 0..4095, bijective
        int xcd = g & 7;
        int i   = g >> 3;
        bmv[tt] = (xcd >> 2) * 32 + (i >> 4);
        bnv[tt] = (xcd & 3) * 16 + (i & 15);
    }

    auto stage = [&](int bm, int bn, int k0) {
#pragma unroll
        for (int it = 0; it < 4; ++it) {
            int c   = it * 256 + tid;      // 16B chunk index 0..1023
            int row = c >> 3;              // tile row 0..127
            int kc  = c & 7;               // chunk-of-8-bf16 within BK=64
            int gkc = kc ^ (row & 7);      // XOR swizzle on the global side
            const unsigned short* gA = A + (size_t)(bm * 128 + row) * KDIM + k0 + gkc * 8;
            const unsigned short* gB = B + (size_t)(bn * 128 + row) * KDIM + k0 + gkc * 8;
            async16(gA, &As[c * 8]);
            async16(gB, &Bs[c * 8]);
        }
    };

    const float variance = vraw[0] * vraw[0];

    stage(bmv[0], bnv[0], 0);              // prologue for first tile

#pragma unroll
    for (int tt = 0; tt < 2; ++tt) {
        const int bm = bmv[tt];
        const int bn = bnv[tt];

        // transposed C/D: element r of acc[tj][ti] is
        //   out[bm*128+wm+ti*16+l15][bn*128+wn+tj*16+quad*4+r]
        floatx4 acc[4][4];
#pragma unroll
        for (int tj = 0; tj < 4; tj++)
#pragma unroll
            for (int ti = 0; ti < 4; ti++) acc[tj][ti] = (floatx4)0.0f;

#pragma unroll
        for (int t = 0; t < 4; ++t) {
            __syncthreads();               // vmcnt(0) drain: stage(t) resident
#pragma unroll
            for (int ks = 0; ks < 2; ++ks) {
                bf16x8 af[4], bfr[4];
                int kc = ks * 4 + quad;    // k = ks*32 + quad*8 -> chunk index
#pragma unroll
                for (int x = 0; x < 4; ++x) {
                    int mm  = wm + x * 16 + l15;
                    int sA  = mm * 8 + (kc ^ (mm & 7));
                    af[x]   = *(const bf16x8*)&As[sA * 8];
                    int nn  = wn + x * 16 + l15;
                    int sB  = nn * 8 + (kc ^ (nn & 7));
                    bfr[x]  = *(const bf16x8*)&Bs[sB * 8];
                }
                // swapped operands: D'[n][m] -> col(lane&15)=m, row(quad*4+r)=n
#pragma unroll
                for (int tj = 0; tj < 4; ++tj)
#pragma unroll
                    for (int ti = 0; ti < 4; ++ti)
                        acc[tj][ti] = __builtin_amdgcn_mfma_f32_16x16x32_bf16(
                            bfr[tj], af[ti], acc[tj][ti], 0, 0, 0);
            }
            // after compute: free the LDS buffer, then issue next stage so its
            // latency hides under what follows (next K-step, or the epilogue).
            if (!(tt == 1 && t == 3)) {
                __syncthreads();           // all LDS reads of this K-step done
                if (t < 3)            stage(bm, bn, (t + 1) * 64);
                else                  stage(bmv[1], bnv[1], 0);  // tt==0 only
            }
        }

        // epilogue (no LDS): runs while next tile's K0 stage is in flight
#pragma unroll
        for (int ti = 0; ti < 4; ++ti) {
            int row = bm * 128 + wm + ti * 16 + l15;
            float rav = ra[row];
            float* orow = out + (size_t)row * MCOLS;
#pragma unroll
            for (int tj = 0; tj < 4; ++tj) {
                int nbase = bn * 128 + wn + tj * 16 + quad * 4;
                floatx4 rbv = *(const floatx4*)&rb[nbase];
                floatx4 val;
#pragma unroll
                for (int r = 0; r < 4; ++r) {
                    float s = rav + rbv[r] - 2.0f * acc[tj][ti][r];
                    s = fmaxf(s, 0.0f);
                    val[r] = variance * __expf(-0.5f * s);
                }
                *(floatx4*)&orow[nbase] = val;
            }
        }
    }
}

extern "C" void kernel_launch(void* const* d_in, const int* in_sizes, int n_in,
                              void* d_out, int out_size, void* d_ws, size_t ws_size,
                              hipStream_t stream) {
    const float* x1   = (const float*)d_in[0];
    const float* x2   = (const float*)d_in[1];
    const float* araw = (const float*)d_in[2];
    const float* vraw = (const float*)d_in[3];
    float* out = (float*)d_out;

    char* ws = (char*)d_ws;
    float* ra = (float*)(ws + 1024);                      // 8192 f32  @ 1 KiB
    float* rb = (float*)(ws + 1024 + 32768);              // 8192 f32
    unsigned short* Amat = (unsigned short*)(ws + 66560);                            // 4 MiB bf16
    unsigned short* Bmat = (unsigned short*)(ws + 66560 + (size_t)NROWS * KDIM * 2); // 4 MiB bf16

    prep_rows<<<(NROWS + MCOLS) / 4, 256, 0, stream>>>(x1, x2, araw, Amat, Bmat, ra, rb);

    rbf_gemm<<<2048, 256, 0, stream>>>(Amat, Bmat, ra, rb, vraw, out);
}

// Round 7
// 338.737 us; speedup vs baseline: 1.0023x; 1.0023x over previous
//
#include <hip/hip_runtime.h>
#include <stdint.h>

#define NROWS 8192
#define MCOLS 8192
#define KDIM  256

typedef __bf16 bf16x8 __attribute__((ext_vector_type(8)));
typedef float  floatx4 __attribute__((ext_vector_type(4)));
typedef unsigned short ushort4v __attribute__((ext_vector_type(4)));

__device__ __forceinline__ unsigned short f32_to_bf16_rne(float f) {
    unsigned int u = __float_as_uint(f);
    u += 0x7FFFu + ((u >> 16) & 1u);   // round-to-nearest-even
    return (unsigned short)(u >> 16);
}
__device__ __forceinline__ float bf16_to_f32(unsigned short h) {
    return __uint_as_float(((unsigned int)h) << 16);
}

// async 16B global -> LDS (wave-uniform base + lane*16 pattern required)
__device__ __forceinline__ void async16(const void* g, void* l) {
    __builtin_amdgcn_global_load_lds(
        (const __attribute__((address_space(1))) unsigned int*)g,
        (__attribute__((address_space(3))) unsigned int*)l,
        16, 0, 0);
}

// ---------------- kernel 1: row prep with FUSED alpha softmax ----------------
// Each block redundantly computes sa = sqrt(softmax(araw^2)) (256 elems, cheap,
// araw L2-hot) -> one fewer kernel launch. Then one row per WAVE, float4/lane.
__global__ void prep_rows(const float* __restrict__ x1, const float* __restrict__ x2,
                          const float* __restrict__ araw,
                          unsigned short* __restrict__ Amat, unsigned short* __restrict__ Bmat,
                          float* __restrict__ ra, float* __restrict__ rb) {
    __shared__ float sa_lds[256];
    __shared__ float wred[8];
    int tid  = threadIdx.x;
    int wave = tid >> 6;
    int lane = tid & 63;

    // fused softmax (all 256 threads)
    float z = araw[tid];
    z = z * z;
    float m = z;
#pragma unroll
    for (int off = 32; off; off >>= 1) m = fmaxf(m, __shfl_xor(m, off));
    if (lane == 0) wred[wave] = m;
    __syncthreads();
    float mx = fmaxf(fmaxf(wred[0], wred[1]), fmaxf(wred[2], wred[3]));
    float e = __expf(z - mx);
    float s = e;
#pragma unroll
    for (int off = 32; off; off >>= 1) s += __shfl_xor(s, off);
    if (lane == 0) wred[4 + wave] = s;       // disjoint slots: no extra barrier
    __syncthreads();
    float sum = wred[4] + wred[5] + wred[6] + wred[7];
    sa_lds[tid] = sqrtf(e / sum);
    __syncthreads();

    // row scaling: one row per wave
    int grow = blockIdx.x * 4 + wave;          // 0 .. 16383
    const float* x; unsigned short* mat; float* nrm; int row;
    if (grow < NROWS) { x = x1; mat = Amat; nrm = ra; row = grow; }
    else              { x = x2; mat = Bmat; nrm = rb; row = grow - NROWS; }

    floatx4 v  = *(const floatx4*)&x[(size_t)row * KDIM + lane * 4];
    floatx4 sv = *(const floatx4*)&sa_lds[lane * 4];
    ushort4v h;
    float p = 0.0f;
#pragma unroll
    for (int j = 0; j < 4; ++j) {
        float f = v[j] * sv[j];
        unsigned short hh = f32_to_bf16_rne(f);
        h[j] = hh;
        float fv = bf16_to_f32(hh);
        p += fv * fv;
    }
    *(ushort4v*)&mat[(size_t)row * KDIM + lane * 4] = h;
#pragma unroll
    for (int off = 32; off; off >>= 1) p += __shfl_xor(p, off);
    if (lane == 0) nrm[row] = p;
}

// ---------------- kernel 2: NT-GEMM + fused RBF epilogue ---------------------
// out = var*exp(-0.5*max(ra_i - 2*sum_k A[i,k]B[j,k] + rb_j, 0))
// Tile 128x128, BK=64, 4 waves (2x2), each wave 64x64 via 4x4 of 16x16x32 MFMA.
// v6 = v4 (best measured structure, ~134us kernel portion) + ONE change:
//   __launch_bounds__(256, 4): cap VGPR at 128 to GUARANTEE 4 blocks/CU.
//   v4's unconstrained regalloc (64 acc + 32 operand VGPRs + stage addresses)
//   plausibly landed at 150-170 VGPR -> 3 blocks/CU; this write-bound kernel
//   lives on cross-block TLP to hide stage latency + store drain.
//   (v5's persistent 2-tile scheme REGRESSED: __syncthreads drains vmcnt(0)
//   which includes epilogue STORES -> tile0's HBM store drain serialized
//   before tile1's compute. Reverted to independent blocks.)
// Kept: single-buffered 32 KiB LDS, transposed acc (mfma(b,a)) -> dwordx4
//   stores, XCD-slab swizzle, XOR LDS swizzle, fused prep (v5).
__global__ __launch_bounds__(256, 4) void rbf_gemm(
    const unsigned short* __restrict__ A, const unsigned short* __restrict__ B,
    const float* __restrict__ ra, const float* __restrict__ rb,
    const float* __restrict__ vraw, float* __restrict__ out)
{
    __shared__ unsigned short As[128 * 64];   // 16 KiB
    __shared__ unsigned short Bs[128 * 64];   // 16 KiB

    const int tid  = threadIdx.x;
    const int lane = tid & 63;
    const int wave = tid >> 6;

    // XCD-slab swizzle: each XCD owns a 32(bm) x 16(bn) region of the 64x64 grid
    // -> per-XCD panel working set 3 MiB < 4 MiB L2. Bijective (4096 % 8 == 0).
    const int g   = blockIdx.y * gridDim.x + blockIdx.x;
    const int xcd = g & 7;
    const int i   = g >> 3;
    const int bm  = (xcd >> 2) * 32 + (i >> 4);
    const int bn  = (xcd & 3) * 16 + (i & 15);

    const int wm = (wave & 1) * 64;
    const int wn = (wave >> 1) * 64;
    const int quad = lane >> 4;
    const int l15  = lane & 15;

    // transposed C/D: element r of acc[tj][ti] is
    //   out[bm*128+wm+ti*16+l15][bn*128+wn+tj*16+quad*4+r]
    floatx4 acc[4][4];
#pragma unroll
    for (int tj = 0; tj < 4; tj++)
#pragma unroll
        for (int ti = 0; ti < 4; ti++) acc[tj][ti] = (floatx4)0.0f;

    for (int t = 0; t < 4; ++t) {
        int k0 = t * 64;
#pragma unroll
        for (int it = 0; it < 4; ++it) {
            int c   = it * 256 + tid;      // 16B chunk index 0..1023
            int row = c >> 3;              // tile row 0..127
            int kc  = c & 7;               // chunk-of-8-bf16 within BK=64
            int gkc = kc ^ (row & 7);      // XOR swizzle on the global side
            const unsigned short* gA = A + (size_t)(bm * 128 + row) * KDIM + k0 + gkc * 8;
            const unsigned short* gB = B + (size_t)(bn * 128 + row) * KDIM + k0 + gkc * 8;
            async16(gA, &As[c * 8]);
            async16(gB, &Bs[c * 8]);
        }
        __syncthreads();                   // stage resident

#pragma unroll
        for (int ks = 0; ks < 2; ++ks) {
            bf16x8 af[4], bfr[4];
            int kc = ks * 4 + quad;        // k = ks*32 + quad*8 -> chunk index
#pragma unroll
            for (int x = 0; x < 4; ++x) {
                int mm  = wm + x * 16 + l15;
                int sA  = mm * 8 + (kc ^ (mm & 7));
                af[x]   = *(const bf16x8*)&As[sA * 8];
                int nn  = wn + x * 16 + l15;
                int sB  = nn * 8 + (kc ^ (nn & 7));
                bfr[x]  = *(const bf16x8*)&Bs[sB * 8];
            }
            // swapped operands: D'[n][m] -> col(lane&15)=m, row(quad*4+r)=n
#pragma unroll
            for (int tj = 0; tj < 4; ++tj)
#pragma unroll
                for (int ti = 0; ti < 4; ++ti)
                    acc[tj][ti] = __builtin_amdgcn_mfma_f32_16x16x32_bf16(
                        bfr[tj], af[ti], acc[tj][ti], 0, 0, 0);
        }
        if (t < 3) __syncthreads();        // protect LDS before next stage
    }

    // epilogue: per (ti,tj) one float4 store of 4 consecutive columns
    float variance = vraw[0] * vraw[0];
#pragma unroll
    for (int ti = 0; ti < 4; ++ti) {
        int row = bm * 128 + wm + ti * 16 + l15;
        float rav = ra[row];
        float* orow = out + (size_t)row * MCOLS;
#pragma unroll
        for (int tj = 0; tj < 4; ++tj) {
            int nbase = bn * 128 + wn + tj * 16 + quad * 4;
            floatx4 rbv = *(const floatx4*)&rb[nbase];
            floatx4 val;
#pragma unroll
            for (int r = 0; r < 4; ++r) {
                float s = rav + rbv[r] - 2.0f * acc[tj][ti][r];
                s = fmaxf(s, 0.0f);
                val[r] = variance * __expf(-0.5f * s);
            }
            *(floatx4*)&orow[nbase] = val;
        }
    }
}

extern "C" void kernel_launch(void* const* d_in, const int* in_sizes, int n_in,
                              void* d_out, int out_size, void* d_ws, size_t ws_size,
                              hipStream_t stream) {
    const float* x1   = (const float*)d_in[0];
    const float* x2   = (const float*)d_in[1];
    const float* araw = (const float*)d_in[2];
    const float* vraw = (const float*)d_in[3];
    float* out = (float*)d_out;

    char* ws = (char*)d_ws;
    float* ra = (float*)(ws + 1024);                      // 8192 f32  @ 1 KiB
    float* rb = (float*)(ws + 1024 + 32768);              // 8192 f32
    unsigned short* Amat = (unsigned short*)(ws + 66560);                            // 4 MiB bf16
    unsigned short* Bmat = (unsigned short*)(ws + 66560 + (size_t)NROWS * KDIM * 2); // 4 MiB bf16

    prep_rows<<<(NROWS + MCOLS) / 4, 256, 0, stream>>>(x1, x2, araw, Amat, Bmat, ra, rb);

    dim3 grid(MCOLS / 128, NROWS / 128);
    rbf_gemm<<<grid, 256, 0, stream>>>(Amat, Bmat, ra, rb, vraw, out);
}